// Round 1
// baseline (1345.575 us; speedup 1.0000x reference)
//
#include <hip/hip_runtime.h>
#include <hip/hip_bf16.h>
#include <stdint.h>

// Problem constants (fixed by the reference file)
#define B_  8192
#define L_  2048
#define NF_ 8

typedef __bf16 bf16_t;
typedef __bf16 bf16x8 __attribute__((ext_vector_type(8)));
typedef __bf16 bf16x4 __attribute__((ext_vector_type(4)));
typedef float  floatx4 __attribute__((ext_vector_type(4)));

// fp32 -> bf16 round-to-nearest-even (inputs are well-conditioned; no NaN path)
__device__ __forceinline__ bf16_t f2bf(float f) {
    union { float f; uint32_t u; } a; a.f = f;
    uint32_t r = a.u + 0x7fffu + ((a.u >> 16) & 1u);
    union { uint16_t s; bf16_t b; } o; o.s = (uint16_t)(r >> 16);
    return o.b;
}

// async global->LDS, 16B per lane. LDS dest is wave-uniform base + lane*16.
#define GLD16(gp, lp)                                                          \
    __builtin_amdgcn_global_load_lds(                                          \
        (const __attribute__((address_space(1))) void*)(gp),                   \
        (__attribute__((address_space(3))) void*)(lp), 16, 0, 0)

// ---------------------------------------------------------------------------
// fp32 -> bf16 bulk conversion. One float4 per thread; grid sized so
// total threads == n/4 exactly (all our sizes are multiples of 1024).
// ---------------------------------------------------------------------------
__global__ __launch_bounds__(256) void cvt_kernel(const float* __restrict__ s,
                                                  bf16_t* __restrict__ d) {
    const int i = blockIdx.x * 256 + threadIdx.x;
    float4 f = ((const float4*)s)[i];
    bf16x4 o = { f2bf(f.x), f2bf(f.y), f2bf(f.z), f2bf(f.w) };
    ((bf16x4*)d)[i] = o;
}

// ---------------------------------------------------------------------------
// C[M,N] = A[M,K] * W[N,K]^T + bias   (bf16 in, fp32 out)
// M=8192, N=K=2048 hardcoded. 128x128 tile, BK=32, 256 threads = 4 waves,
// each wave does a 64x64 subtile as 4x4 MFMA 16x16x32 tiles.
// ---------------------------------------------------------------------------
__global__ __launch_bounds__(256) void gemm_bt_kernel(
    const bf16_t* __restrict__ A,   // [M, K]
    const bf16_t* __restrict__ W,   // [N, K]
    const float*  __restrict__ bias,// [N]
    float* __restrict__ C)          // [M, N]
{
    constexpr int K = L_;
    constexpr int N = L_;
    __shared__ alignas(16) bf16_t sA[128 * 32];
    __shared__ alignas(16) bf16_t sB[128 * 32];

    const int tid  = threadIdx.x;
    const int lane = tid & 63;
    const int wave = tid >> 6;
    const int wm   = wave >> 1;   // 0..1
    const int wn   = wave & 1;    // 0..1
    const int tm   = blockIdx.y * 128;
    const int tn   = blockIdx.x * 128;

    // staging: thread t loads 8 bf16 at tile (row = t/4, col = (t%4)*8);
    // two issues per tile (rows 0..63 then 64..127). LDS is row-major [128][32],
    // which is exactly lane-order-contiguous as global_load_lds requires.
    const bf16_t* Ag0 = A + (tm + (tid >> 2)) * K + (tid & 3) * 8;
    const bf16_t* Ag1 = Ag0 + 64 * K;
    const bf16_t* Wg0 = W + (tn + (tid >> 2)) * K + (tid & 3) * 8;
    const bf16_t* Wg1 = Wg0 + 64 * K;
    bf16_t* sAp = sA + tid * 8;
    bf16_t* sBp = sB + tid * 8;

    floatx4 acc[4][4] = {};

    const int ra = wm * 64 + (lane & 15);   // A fragment row within tile
    const int rb = wn * 64 + (lane & 15);   // W fragment row within tile
    const int kq = (lane >> 4) * 8;         // k offset within BK

    for (int kt = 0; kt < K; kt += 32) {
        GLD16(Ag0 + kt, sAp);
        GLD16(Ag1 + kt, sAp + 2048);
        GLD16(Wg0 + kt, sBp);
        GLD16(Wg1 + kt, sBp + 2048);
        asm volatile("s_waitcnt vmcnt(0)" ::: "memory");
        __syncthreads();

        bf16x8 af[4], bw[4];
#pragma unroll
        for (int i = 0; i < 4; ++i)
            af[i] = *(const bf16x8*)(sA + (ra + i * 16) * 32 + kq);
#pragma unroll
        for (int i = 0; i < 4; ++i)
            bw[i] = *(const bf16x8*)(sB + (rb + i * 16) * 32 + kq);

#pragma unroll
        for (int mi = 0; mi < 4; ++mi)
#pragma unroll
            for (int ni = 0; ni < 4; ++ni)
                acc[mi][ni] = __builtin_amdgcn_mfma_f32_16x16x32_bf16(
                    af[mi], bw[ni], acc[mi][ni], 0, 0, 0);
        __syncthreads();
    }

    // epilogue: C/D layout col = lane&15, row = (lane>>4)*4 + reg
    const int row0 = tm + wm * 64 + (lane >> 4) * 4;
    const int col0 = tn + wn * 64 + (lane & 15);
#pragma unroll
    for (int ni = 0; ni < 4; ++ni) {
        const int col = col0 + ni * 16;
        const float bv = bias[col];
#pragma unroll
        for (int mi = 0; mi < 4; ++mi) {
#pragma unroll
            for (int r = 0; r < 4; ++r) {
                C[(row0 + mi * 16 + r) * N + col] = acc[mi][ni][r] + bv;
            }
        }
    }
}

// ---------------------------------------------------------------------------
// Householder reflection: z -= 2 v (v.z)/(v.v), one block per row.
// Also emits bf16(v) as the next GEMM's A operand (fused downcast).
// ---------------------------------------------------------------------------
__global__ __launch_bounds__(256) void hflow_kernel(
    const float* __restrict__ V, const float* __restrict__ zin,
    float* __restrict__ zout, bf16_t* __restrict__ Aout, int writeA)
{
    const int row = blockIdx.x;
    const int tid = threadIdx.x;
    const float4* v4 = (const float4*)(V + (size_t)row * L_);
    const float4* z4 = (const float4*)(zin + (size_t)row * L_);
    float4 v0 = v4[tid], v1 = v4[tid + 256];
    float4 z0 = z4[tid], z1 = z4[tid + 256];

    float vz = v0.x * z0.x + v0.y * z0.y + v0.z * z0.z + v0.w * z0.w
             + v1.x * z1.x + v1.y * z1.y + v1.z * z1.z + v1.w * z1.w;
    float vv = v0.x * v0.x + v0.y * v0.y + v0.z * v0.z + v0.w * v0.w
             + v1.x * v1.x + v1.y * v1.y + v1.z * v1.z + v1.w * v1.w;

#pragma unroll
    for (int off = 32; off > 0; off >>= 1) {
        vz += __shfl_down(vz, off);
        vv += __shfl_down(vv, off);
    }
    __shared__ float svz[4], svv[4];
    if ((tid & 63) == 0) { svz[tid >> 6] = vz; svv[tid >> 6] = vv; }
    __syncthreads();
    const float tvz = svz[0] + svz[1] + svz[2] + svz[3];
    const float tvv = svv[0] + svv[1] + svv[2] + svv[3];
    const float s = 2.0f * tvz / tvv;

    float4 o0, o1;
    o0.x = z0.x - s * v0.x; o0.y = z0.y - s * v0.y;
    o0.z = z0.z - s * v0.z; o0.w = z0.w - s * v0.w;
    o1.x = z1.x - s * v1.x; o1.y = z1.y - s * v1.y;
    o1.z = z1.z - s * v1.z; o1.w = z1.w - s * v1.w;

    float4* zo = (float4*)(zout + (size_t)row * L_);
    zo[tid] = o0;
    zo[tid + 256] = o1;

    if (writeA) {
        bf16x4 a0 = { f2bf(v0.x), f2bf(v0.y), f2bf(v0.z), f2bf(v0.w) };
        bf16x4 a1 = { f2bf(v1.x), f2bf(v1.y), f2bf(v1.z), f2bf(v1.w) };
        bf16x4* ao = (bf16x4*)(Aout + (size_t)row * L_);
        ao[tid] = a0;
        ao[tid + 256] = a1;
    }
}

// ---------------------------------------------------------------------------
extern "C" void kernel_launch(void* const* d_in, const int* in_sizes, int n_in,
                              void* d_out, int out_size, void* d_ws, size_t ws_size,
                              hipStream_t stream) {
    (void)in_sizes; (void)n_in; (void)out_size; (void)ws_size;
    const float* z_in   = (const float*)d_in[0];  // [B, L]
    const float* h_last = (const float*)d_in[1];  // [B, H]
    const float* W0     = (const float*)d_in[2];  // [L, H]
    const float* b0     = (const float*)d_in[3];  // [L]
    const float* Wsp    = (const float*)d_in[4];  // [NF-1, L, L]
    const float* bsp    = (const float*)d_in[5];  // [NF-1, L]
    float* z_out = (float*)d_out;

    // workspace layout: bf16 weights (all 8) | bf16 A (current v) | fp32 V
    char* ws = (char*)d_ws;
    bf16_t* Wbf  = (bf16_t*)ws;                                        // NF*L*L
    bf16_t* Abuf = (bf16_t*)(ws + (size_t)NF_ * L_ * L_ * 2);          // B*L
    float*  Vbuf = (float*)(ws + (size_t)NF_ * L_ * L_ * 2
                               + (size_t)B_ * L_ * 2);                  // B*L

    // convert weights + h_last to bf16 (1024 elems per block)
    cvt_kernel<<<(L_ * L_) / 1024, 256, 0, stream>>>(W0, Wbf);
    cvt_kernel<<<((NF_ - 1) * L_ * L_) / 1024, 256, 0, stream>>>(
        Wsp, Wbf + (size_t)L_ * L_);
    cvt_kernel<<<(B_ * L_) / 1024, 256, 0, stream>>>(h_last, Abuf);

    dim3 ggrid(L_ / 128, B_ / 128);
    for (int j = 0; j < NF_; ++j) {
        const float* bias = (j == 0) ? b0 : bsp + (size_t)(j - 1) * L_;
        const bf16_t* Wj = Wbf + (size_t)j * L_ * L_;
        gemm_bt_kernel<<<ggrid, 256, 0, stream>>>(Abuf, Wj, bias, Vbuf);
        hflow_kernel<<<B_, 256, 0, stream>>>(
            Vbuf, (j == 0) ? z_in : z_out, z_out, Abuf,
            (j < NF_ - 1) ? 1 : 0);
    }
}

// Round 2
// 1228.684 us; speedup vs baseline: 1.0951x; 1.0951x over previous
//
#include <hip/hip_runtime.h>
#include <hip/hip_bf16.h>
#include <stdint.h>

// Problem constants (fixed by the reference file)
#define B_  8192
#define L_  2048
#define NF_ 8

typedef __bf16 bf16_t;
typedef __bf16 bf16x8 __attribute__((ext_vector_type(8)));
typedef __bf16 bf16x4 __attribute__((ext_vector_type(4)));
typedef float  floatx4 __attribute__((ext_vector_type(4)));

// fp32 -> bf16 round-to-nearest-even
__device__ __forceinline__ bf16_t f2bf(float f) {
    union { float f; uint32_t u; } a; a.f = f;
    uint32_t r = a.u + 0x7fffu + ((a.u >> 16) & 1u);
    union { uint16_t s; bf16_t b; } o; o.s = (uint16_t)(r >> 16);
    return o.b;
}

// async global->LDS, 16B per lane. LDS dest is wave-uniform base + lane*16.
#define GLD16(gp, lp)                                                          \
    __builtin_amdgcn_global_load_lds(                                          \
        (const __attribute__((address_space(1))) void*)(gp),                   \
        (__attribute__((address_space(3))) void*)(lp), 16, 0, 0)

// ---------------------------------------------------------------------------
// fp32 -> bf16 bulk conversion. One float4 per thread.
// ---------------------------------------------------------------------------
__global__ __launch_bounds__(256) void cvt_kernel(const float* __restrict__ s,
                                                  bf16_t* __restrict__ d) {
    const int i = blockIdx.x * 256 + threadIdx.x;
    float4 f = ((const float4*)s)[i];
    bf16x4 o = { f2bf(f.x), f2bf(f.y), f2bf(f.z), f2bf(f.w) };
    ((bf16x4*)d)[i] = o;
}

// ---------------------------------------------------------------------------
// Vb[M,N] = bf16( A[M,K] * W[N,K]^T + bias )   (bf16 in, bf16 out)
// M=8192, N=K=2048. 128x128 tile, BK=32, 256 threads = 4 waves,
// each wave a 64x64 subtile as 4x4 MFMA 16x16x32.
// LDS XOR swizzle: logical (row r, 16B-chunk c) lives at slot 4r + (c ^ ((r>>1)&3)).
// Staging side realizes this by permuting WHICH global chunk each lane fetches
// (global_load_lds dest is fixed lane-contiguous). Reader xors the same term.
// Bank-group for a read = (4*(R&7) + q^((R>>1)&3)) mod 8: bijective per 8-lane
// group -> conflict-free ds_read_b128.
// ---------------------------------------------------------------------------
__global__ __launch_bounds__(256) void gemm_bt_kernel(
    const bf16_t* __restrict__ A,   // [M, K]
    const bf16_t* __restrict__ W,   // [N, K]
    const float*  __restrict__ bias,// [N]
    bf16_t* __restrict__ Vb)        // [M, N] bf16 (also next A)
{
    constexpr int K = L_;
    constexpr int N = L_;
    __shared__ alignas(16) bf16_t sA[128 * 32];
    __shared__ alignas(16) bf16_t sB[128 * 32];

    const int tid  = threadIdx.x;
    const int lane = tid & 63;
    const int wave = tid >> 6;
    const int wm   = wave >> 1;   // 0..1
    const int wn   = wave & 1;    // 0..1
    const int tm   = blockIdx.y * 128;
    const int tn   = blockIdx.x * 128;

    // staging: thread t fills LDS slot t (16B) and slot t+256.
    // logical chunk fetched for slot t: (t&3) ^ ((t>>3)&3)  [row = t>>2]
    const int srow = tid >> 2;
    const int schk = (tid & 3) ^ ((tid >> 3) & 3);
    const bf16_t* Ag0 = A + (size_t)(tm + srow) * K + schk * 8;
    const bf16_t* Ag1 = Ag0 + 64 * K;
    const bf16_t* Wg0 = W + (size_t)(tn + srow) * K + schk * 8;
    const bf16_t* Wg1 = Wg0 + 64 * K;
    bf16_t* sAp = sA + tid * 8;
    bf16_t* sBp = sB + tid * 8;

    floatx4 acc[4][4] = {};

    const int ra = wm * 64 + (lane & 15);   // A fragment row within tile
    const int rb = wn * 64 + (lane & 15);   // W fragment row within tile
    // swizzled chunk for reads: q ^ ((R>>1)&3); R&7 parity fixed per lane
    const int swz = ((lane >> 4) ^ (((lane & 15) >> 1) & 3)) * 8; // elem offset

    for (int kt = 0; kt < K; kt += 32) {
        GLD16(Ag0 + kt, sAp);
        GLD16(Ag1 + kt, sAp + 2048);
        GLD16(Wg0 + kt, sBp);
        GLD16(Wg1 + kt, sBp + 2048);
        asm volatile("s_waitcnt vmcnt(0)" ::: "memory");
        __syncthreads();

        bf16x8 af[4], bw[4];
#pragma unroll
        for (int i = 0; i < 4; ++i)
            af[i] = *(const bf16x8*)(sA + (ra + i * 16) * 32 + swz);
#pragma unroll
        for (int i = 0; i < 4; ++i)
            bw[i] = *(const bf16x8*)(sB + (rb + i * 16) * 32 + swz);

#pragma unroll
        for (int mi = 0; mi < 4; ++mi)
#pragma unroll
            for (int ni = 0; ni < 4; ++ni)
                acc[mi][ni] = __builtin_amdgcn_mfma_f32_16x16x32_bf16(
                    af[mi], bw[ni], acc[mi][ni], 0, 0, 0);
        __syncthreads();
    }

    // epilogue: C/D layout col = lane&15, row = (lane>>4)*4 + reg.
    // bf16 scalar stores; 16 lanes = 32B contiguous, L2 merges rows to lines.
    const int row0 = tm + wm * 64 + (lane >> 4) * 4;
    const int col0 = tn + wn * 64 + (lane & 15);
#pragma unroll
    for (int ni = 0; ni < 4; ++ni) {
        const int col = col0 + ni * 16;
        const float bv = bias[col];
#pragma unroll
        for (int mi = 0; mi < 4; ++mi) {
#pragma unroll
            for (int r = 0; r < 4; ++r) {
                Vb[(size_t)(row0 + mi * 16 + r) * N + col] = f2bf(acc[mi][ni][r] + bv);
            }
        }
    }
}

// ---------------------------------------------------------------------------
// Householder reflection: z -= 2 v (v.z)/(v.v), one block per row, v in bf16.
// ---------------------------------------------------------------------------
__global__ __launch_bounds__(256) void hflow_kernel(
    const bf16_t* __restrict__ V, const float* __restrict__ zin,
    float* __restrict__ zout)
{
    const int row = blockIdx.x;
    const int tid = threadIdx.x;
    bf16x8 v8 = ((const bf16x8*)(V + (size_t)row * L_))[tid];
    const float4* z4 = (const float4*)(zin + (size_t)row * L_);
    float4 z0 = z4[2 * tid], z1 = z4[2 * tid + 1];

    float vf[8];
#pragma unroll
    for (int i = 0; i < 8; ++i) vf[i] = (float)v8[i];

    float vz = vf[0] * z0.x + vf[1] * z0.y + vf[2] * z0.z + vf[3] * z0.w
             + vf[4] * z1.x + vf[5] * z1.y + vf[6] * z1.z + vf[7] * z1.w;
    float vv = vf[0] * vf[0] + vf[1] * vf[1] + vf[2] * vf[2] + vf[3] * vf[3]
             + vf[4] * vf[4] + vf[5] * vf[5] + vf[6] * vf[6] + vf[7] * vf[7];

#pragma unroll
    for (int off = 32; off > 0; off >>= 1) {
        vz += __shfl_down(vz, off);
        vv += __shfl_down(vv, off);
    }
    __shared__ float svz[4], svv[4];
    if ((tid & 63) == 0) { svz[tid >> 6] = vz; svv[tid >> 6] = vv; }
    __syncthreads();
    const float tvz = svz[0] + svz[1] + svz[2] + svz[3];
    const float tvv = svv[0] + svv[1] + svv[2] + svv[3];
    const float s = 2.0f * tvz / tvv;

    float4 o0, o1;
    o0.x = z0.x - s * vf[0]; o0.y = z0.y - s * vf[1];
    o0.z = z0.z - s * vf[2]; o0.w = z0.w - s * vf[3];
    o1.x = z1.x - s * vf[4]; o1.y = z1.y - s * vf[5];
    o1.z = z1.z - s * vf[6]; o1.w = z1.w - s * vf[7];

    float4* zo = (float4*)(zout + (size_t)row * L_);
    zo[2 * tid] = o0;
    zo[2 * tid + 1] = o1;
}

// ---------------------------------------------------------------------------
extern "C" void kernel_launch(void* const* d_in, const int* in_sizes, int n_in,
                              void* d_out, int out_size, void* d_ws, size_t ws_size,
                              hipStream_t stream) {
    (void)in_sizes; (void)n_in; (void)out_size; (void)ws_size;
    const float* z_in   = (const float*)d_in[0];  // [B, L]
    const float* h_last = (const float*)d_in[1];  // [B, H]
    const float* W0     = (const float*)d_in[2];  // [L, H]
    const float* b0     = (const float*)d_in[3];  // [L]
    const float* Wsp    = (const float*)d_in[4];  // [NF-1, L, L]
    const float* bsp    = (const float*)d_in[5];  // [NF-1, L]
    float* z_out = (float*)d_out;

    // workspace: bf16 weights (all 8) | bf16 V ping | bf16 V pong
    char* ws = (char*)d_ws;
    bf16_t* Wbf = (bf16_t*)ws;                                        // NF*L*L
    bf16_t* Vp0 = (bf16_t*)(ws + (size_t)NF_ * L_ * L_ * 2);          // B*L
    bf16_t* Vp1 = Vp0 + (size_t)B_ * L_;                              // B*L

    cvt_kernel<<<(L_ * L_) / 1024, 256, 0, stream>>>(W0, Wbf);
    cvt_kernel<<<((NF_ - 1) * L_ * L_) / 1024, 256, 0, stream>>>(
        Wsp, Wbf + (size_t)L_ * L_);
    cvt_kernel<<<(B_ * L_) / 1024, 256, 0, stream>>>(h_last, Vp0);

    dim3 ggrid(L_ / 128, B_ / 128);
    bf16_t* bufs[2] = { Vp0, Vp1 };
    for (int j = 0; j < NF_; ++j) {
        const float* bias = (j == 0) ? b0 : bsp + (size_t)(j - 1) * L_;
        const bf16_t* Wj = Wbf + (size_t)j * L_ * L_;
        bf16_t* Ain = bufs[j & 1];
        bf16_t* Vout = bufs[(j + 1) & 1];
        gemm_bt_kernel<<<ggrid, 256, 0, stream>>>(Ain, Wj, bias, Vout);
        hflow_kernel<<<B_, 256, 0, stream>>>(
            Vout, (j == 0) ? z_in : z_out, z_out);
    }
}

// Round 4
// 1040.041 us; speedup vs baseline: 1.2938x; 1.1814x over previous
//
#include <hip/hip_runtime.h>
#include <hip/hip_bf16.h>
#include <stdint.h>

// Problem constants (fixed by the reference file)
#define B_  8192
#define L_  2048
#define NF_ 8

typedef __bf16 bf16_t;
typedef __bf16 bf16x8 __attribute__((ext_vector_type(8)));
typedef __bf16 bf16x4 __attribute__((ext_vector_type(4)));
typedef float  floatx4 __attribute__((ext_vector_type(4)));

// fp32 -> bf16 round-to-nearest-even
__device__ __forceinline__ bf16_t f2bf(float f) {
    union { float f; uint32_t u; } a; a.f = f;
    uint32_t r = a.u + 0x7fffu + ((a.u >> 16) & 1u);
    union { uint16_t s; bf16_t b; } o; o.s = (uint16_t)(r >> 16);
    return o.b;
}

// async global->LDS, 16B per lane. LDS dest is wave-uniform base + lane*16.
#define GLD16(gp, lp)                                                          \
    __builtin_amdgcn_global_load_lds(                                          \
        (const __attribute__((address_space(1))) void*)(gp),                   \
        (__attribute__((address_space(3))) void*)(lp), 16, 0, 0)

// ---------------------------------------------------------------------------
// fp32 -> bf16 bulk conversion. One float4 per thread.
// ---------------------------------------------------------------------------
__global__ __launch_bounds__(256) void cvt_kernel(const float* __restrict__ s,
                                                  bf16_t* __restrict__ d) {
    const int i = blockIdx.x * 256 + threadIdx.x;
    float4 f = ((const float4*)s)[i];
    bf16x4 o = { f2bf(f.x), f2bf(f.y), f2bf(f.z), f2bf(f.w) };
    ((bf16x4*)d)[i] = o;
}

// ---------------------------------------------------------------------------
// Vb[M,N] = bf16( A[M,K] * W[N,K]^T + bias )   (bf16 in, bf16 out)
// M=8192, N=K=2048. 128x128 tile, BK=64 (32 iters, 32 MFMA/wave per barrier),
// 256 threads = 4 waves, each wave a 64x64 subtile as 4x4 MFMA 16x16x32.
//
// LDS swizzle (rows of 8 x 16B chunks): logical (row r, chunk c) lives at
// physical slot r*8 + (c ^ (r&7)). ds_read_b128: any 8 consecutive lanes read
// 8 consecutive rows at fixed c -> 8 distinct slot%8 -> conflict-free.
// Staging slot s = tid + i*256: r=(tid>>3)+32i, p=tid&7, so the logical chunk
// c = (tid&7) ^ ((tid>>3)&7) is i-invariant -> one base pointer per thread.
// ---------------------------------------------------------------------------
__global__ __launch_bounds__(256, 4) void gemm_bt_kernel(
    const bf16_t* __restrict__ A,   // [M, K]
    const bf16_t* __restrict__ W,   // [N, K]
    const float*  __restrict__ bias,// [N]
    bf16_t* __restrict__ Vb)        // [M, N] bf16 (also next A)
{
    constexpr int K = L_;
    constexpr int N = L_;
    __shared__ alignas(16) bf16_t sA[128 * 64];
    __shared__ alignas(16) bf16_t sB[128 * 64];

    const int tid  = threadIdx.x;
    const int lane = tid & 63;
    const int wave = tid >> 6;
    const int wm   = wave >> 1;   // 0..1
    const int wn   = wave & 1;    // 0..1
    const int tm   = blockIdx.y * 128;
    const int tn   = blockIdx.x * 128;

    const int srow = tid >> 3;
    const int schk = (tid & 7) ^ (srow & 7);
    const bf16_t* Ag = A + (size_t)(tm + srow) * K + schk * 8;
    const bf16_t* Wg = W + (size_t)(tn + srow) * K + schk * 8;
    bf16_t* sAp = sA + tid * 8;
    bf16_t* sBp = sB + tid * 8;

    floatx4 acc[4][4] = {};

    const int ra = wm * 64 + (lane & 15);   // A fragment row within tile
    const int rb = wn * 64 + (lane & 15);   // W fragment row within tile
    const int q  = lane >> 4;               // k-quad 0..3
    const int rx = lane & 7;                // (read row)&7 — 16i-invariant

    for (int kt = 0; kt < K; kt += 64) {
#pragma unroll
        for (int i = 0; i < 4; ++i) {
            GLD16(Ag + kt + (size_t)(32 * i) * K, sAp + i * 2048);
            GLD16(Wg + kt + (size_t)(32 * i) * K, sBp + i * 2048);
        }
        asm volatile("s_waitcnt vmcnt(0)" ::: "memory");
        __syncthreads();

#pragma unroll
        for (int ks = 0; ks < 2; ++ks) {
            const int c = ks * 4 + q;
            const int pc = (c ^ rx) * 8;    // physical chunk -> element offset
            bf16x8 af[4], bw[4];
#pragma unroll
            for (int i = 0; i < 4; ++i) {
                af[i] = *(const bf16x8*)(sA + (ra + i * 16) * 64 + pc);
                bw[i] = *(const bf16x8*)(sB + (rb + i * 16) * 64 + pc);
            }
#pragma unroll
            for (int mi = 0; mi < 4; ++mi)
#pragma unroll
                for (int ni = 0; ni < 4; ++ni)
                    acc[mi][ni] = __builtin_amdgcn_mfma_f32_16x16x32_bf16(
                        af[mi], bw[ni], acc[mi][ni], 0, 0, 0);
        }
        __syncthreads();
    }

    // epilogue: C/D layout col = lane&15, row = (lane>>4)*4 + reg
    const int row0 = tm + wm * 64 + (lane >> 4) * 4;
    const int col0 = tn + wn * 64 + (lane & 15);
#pragma unroll
    for (int ni = 0; ni < 4; ++ni) {
        const int col = col0 + ni * 16;
        const float bv = bias[col];
#pragma unroll
        for (int mi = 0; mi < 4; ++mi) {
#pragma unroll
            for (int r = 0; r < 4; ++r) {
                Vb[(size_t)(row0 + mi * 16 + r) * N + col] = f2bf(acc[mi][ni][r] + bv);
            }
        }
    }
}

// ---------------------------------------------------------------------------
// Householder reflection: z -= 2 v (v.z)/(v.v). ONE WAVE PER ROW (no LDS,
// no __syncthreads). 256-thread block = 4 rows. Butterfly shfl_xor reduce.
// v chunk j = elements 8*(lane+64j) .. +8  <->  z4[2*(lane+64j)], z4[2*(lane+64j)+1]
// (matched element ranges — this pairing was the round-3 bug).
// ---------------------------------------------------------------------------
__global__ __launch_bounds__(256, 4) void hflow_kernel(
    const bf16_t* __restrict__ V, const float* __restrict__ zin,
    float* __restrict__ zout)
{
    const int lane = threadIdx.x & 63;
    const int row  = blockIdx.x * 4 + (threadIdx.x >> 6);
    const bf16x8* v8 = (const bf16x8*)(V + (size_t)row * L_);
    const float4* z4 = (const float4*)(zin + (size_t)row * L_);
    float4*       zo = (float4*)(zout + (size_t)row * L_);

    bf16x8 v[4];
    float4 z[8];
#pragma unroll
    for (int j = 0; j < 4; ++j) {
        const int idx = lane + 64 * j;
        v[j]         = v8[idx];
        z[2 * j]     = z4[2 * idx];
        z[2 * j + 1] = z4[2 * idx + 1];
    }

    float vf[32];
#pragma unroll
    for (int j = 0; j < 4; ++j)
#pragma unroll
        for (int e = 0; e < 8; ++e) vf[j * 8 + e] = (float)v[j][e];

    float vz = 0.f, vv = 0.f;
#pragma unroll
    for (int j = 0; j < 4; ++j) {
        const float* f = vf + j * 8;
        vz += f[0] * z[2*j].x + f[1] * z[2*j].y + f[2] * z[2*j].z + f[3] * z[2*j].w
            + f[4] * z[2*j+1].x + f[5] * z[2*j+1].y + f[6] * z[2*j+1].z + f[7] * z[2*j+1].w;
        vv += f[0]*f[0] + f[1]*f[1] + f[2]*f[2] + f[3]*f[3]
            + f[4]*f[4] + f[5]*f[5] + f[6]*f[6] + f[7]*f[7];
    }

#pragma unroll
    for (int off = 1; off < 64; off <<= 1) {
        vz += __shfl_xor(vz, off);
        vv += __shfl_xor(vv, off);
    }
    const float s = 2.0f * vz / vv;

#pragma unroll
    for (int j = 0; j < 4; ++j) {
        const int idx = lane + 64 * j;
        const float* f = vf + j * 8;
        float4 a = z[2*j], b = z[2*j+1];
        a.x -= s * f[0]; a.y -= s * f[1]; a.z -= s * f[2]; a.w -= s * f[3];
        b.x -= s * f[4]; b.y -= s * f[5]; b.z -= s * f[6]; b.w -= s * f[7];
        zo[2 * idx]     = a;
        zo[2 * idx + 1] = b;
    }
}

// ---------------------------------------------------------------------------
extern "C" void kernel_launch(void* const* d_in, const int* in_sizes, int n_in,
                              void* d_out, int out_size, void* d_ws, size_t ws_size,
                              hipStream_t stream) {
    (void)in_sizes; (void)n_in; (void)out_size; (void)ws_size;
    const float* z_in   = (const float*)d_in[0];  // [B, L]
    const float* h_last = (const float*)d_in[1];  // [B, H]
    const float* W0     = (const float*)d_in[2];  // [L, H]
    const float* b0     = (const float*)d_in[3];  // [L]
    const float* Wsp    = (const float*)d_in[4];  // [NF-1, L, L]
    const float* bsp    = (const float*)d_in[5];  // [NF-1, L]
    float* z_out = (float*)d_out;

    // workspace: bf16 weights (all 8) | bf16 V ping | bf16 V pong
    char* ws = (char*)d_ws;
    bf16_t* Wbf = (bf16_t*)ws;                                        // NF*L*L
    bf16_t* Vp0 = (bf16_t*)(ws + (size_t)NF_ * L_ * L_ * 2);          // B*L
    bf16_t* Vp1 = Vp0 + (size_t)B_ * L_;                              // B*L

    cvt_kernel<<<(L_ * L_) / 1024, 256, 0, stream>>>(W0, Wbf);
    cvt_kernel<<<((NF_ - 1) * L_ * L_) / 1024, 256, 0, stream>>>(
        Wsp, Wbf + (size_t)L_ * L_);
    cvt_kernel<<<(B_ * L_) / 1024, 256, 0, stream>>>(h_last, Vp0);

    dim3 ggrid(L_ / 128, B_ / 128);
    bf16_t* bufs[2] = { Vp0, Vp1 };
    for (int j = 0; j < NF_; ++j) {
        const float* bias = (j == 0) ? b0 : bsp + (size_t)(j - 1) * L_;
        const bf16_t* Wj = Wbf + (size_t)j * L_ * L_;
        bf16_t* Ain = bufs[j & 1];
        bf16_t* Vout = bufs[(j + 1) & 1];
        gemm_bt_kernel<<<ggrid, 256, 0, stream>>>(Ain, Wj, bias, Vout);
        hflow_kernel<<<B_ / 4, 256, 0, stream>>>(
            Vout, (j == 0) ? z_in : z_out, z_out);
    }
}